// Round 10
// baseline (1174.210 us; speedup 1.0000x reference)
//
#include <hip/hip_runtime.h>
#include <hip/hip_bf16.h>
#include <hip/hip_cooperative_groups.h>

namespace cg = cooperative_groups;

#define NN 100000
#define EE 1600000

constexpr int SCAN_BLK = 1024;                       // nodes per scan/combine block
constexpr int NB_SCAN  = (NN + SCAN_BLK - 1) / SCAN_BLK;  // 98

// LDS counting-sort CSR build: 8 dst-ranges x 32 edge-chunks
constexpr int NR2 = 8;              // dst ranges (12500 nodes -> 50 KB LDS histogram)
constexpr int RSZ = NN / NR2;       // 12500
constexpr int CH  = 32;             // edge chunks
constexpr int CSZ = EE / CH;        // 50000 edges per chunk (multiple of 4)
constexpr int SCAT_B = CH * NR2;    // 256 scatter blocks in the fused kernel

// ---------------- CSR build (no global atomics) ----------------

__global__ __launch_bounds__(256) void histL_k(const int* __restrict__ ei,
                                               int* __restrict__ CntG) {
    __shared__ int cnt[RSZ];
    int r = blockIdx.x % NR2, c = blockIdx.x / NR2;
    int lo = r * RSZ;
    for (int t = threadIdx.x; t < RSZ; t += 256) cnt[t] = 0;
    __syncthreads();
    const int* __restrict__ dstp = ei + EE;
    int base = c * CSZ;
    int tid = threadIdx.x;
    for (int ii = 0; ii < CSZ; ii += 1024) {
        int off = ii + tid * 4;
        if (off < CSZ) {
            int4 s4 = *(const int4*)&ei[base + off];
            int4 d4 = *(const int4*)&dstp[base + off];
            int dl;
            dl = d4.x - lo; if (dl >= 0 && dl < RSZ && s4.x != d4.x) atomicAdd(&cnt[dl], 1);
            dl = d4.y - lo; if (dl >= 0 && dl < RSZ && s4.y != d4.y) atomicAdd(&cnt[dl], 1);
            dl = d4.z - lo; if (dl >= 0 && dl < RSZ && s4.z != d4.z) atomicAdd(&cnt[dl], 1);
            dl = d4.w - lo; if (dl >= 0 && dl < RSZ && s4.w != d4.w) atomicAdd(&cnt[dl], 1);
        }
    }
    __syncthreads();
    for (int t = threadIdx.x; t < RSZ; t += 256)
        CntG[(size_t)c * NN + lo + t] = cnt[t];
}

// chunk-prefix transform over CntG + per-1024-node partial sums (fused)
__global__ __launch_bounds__(256) void combine_sum_k(int* __restrict__ CntG,
                                                     int* __restrict__ deg,
                                                     int* __restrict__ partials) {
    __shared__ int sh[256];
    int t = threadIdx.x;
    int s_tot = 0;
    #pragma unroll
    for (int k = 0; k < 4; ++k) {
        int d = blockIdx.x * SCAN_BLK + k * 256 + t;
        int run = 0;
        if (d < NN) {
            #pragma unroll 8
            for (int c = 0; c < CH; ++c) {
                int v = CntG[(size_t)c * NN + d];
                CntG[(size_t)c * NN + d] = run;
                run += v;
            }
            deg[d] = run;
        }
        s_tot += run;
    }
    sh[t] = s_tot; __syncthreads();
    for (int off = 128; off > 0; off >>= 1) {
        if (t < off) sh[t] += sh[t + off];
        __syncthreads();
    }
    if (t == 0) partials[blockIdx.x] = sh[0];
}

// rowptr build; the 98-entry partial scan is inlined (cheap per block)
__global__ void scan_final(const int* __restrict__ deg, const int* __restrict__ partials,
                           int* __restrict__ rowptr) {
    __shared__ int sh[256];
    __shared__ int sp[128];
    int t = threadIdx.x;
    if (t < 128) sp[t] = (t < NB_SCAN) ? partials[t] : 0;
    __syncthreads();
    for (int off = 1; off < 128; off <<= 1) {
        int tmp = 0;
        if (t < 128 && t >= off) tmp = sp[t - off];
        __syncthreads();
        if (t < 128) sp[t] += tmp;
        __syncthreads();
    }
    int pref0 = sp[blockIdx.x] - partials[blockIdx.x];   // exclusive prefix of this block

    int base = blockIdx.x * SCAN_BLK + t * 4;
    int v[4]; int s = 0;
    #pragma unroll
    for (int k = 0; k < 4; ++k) { int i = base + k; v[k] = (i < NN) ? deg[i] : 0; s += v[k]; }
    sh[t] = s; __syncthreads();
    for (int off = 1; off < 256; off <<= 1) {
        int tmp = (t >= off) ? sh[t - off] : 0;
        __syncthreads();
        sh[t] += tmp;
        __syncthreads();
    }
    int pref = pref0 + sh[t] - s;
    #pragma unroll
    for (int k = 0; k < 4; ++k) {
        int i = base + k;
        if (i < NN) {
            rowptr[i] = pref; pref += v[k];
            if (i == NN - 1) rowptr[NN] = pref;
        }
    }
}

// ---------------- Fused scatter (CSR col build) || gemm1 ----------------
// Verified in rounds 7-8. Blocks 0..255 run the LDS scatter; blocks 256.. run
// the layer-1 GEMM (x @ W1 + attention scores). Union'd dynamic LDS (50 KB).

__global__ __launch_bounds__(256) void sg1_k(const int* __restrict__ ei,
                                             const int* __restrict__ CntG,
                                             const int* __restrict__ rowptr,
                                             int* __restrict__ col,
                                             const float* __restrict__ xin,
                                             const float* __restrict__ W,
                                             const float* __restrict__ att,
                                             uint2* __restrict__ Hbf,
                                             float* __restrict__ ssrcA,
                                             float* __restrict__ sdst) {
    extern __shared__ char smem[];
    int tid = threadIdx.x;

    if (blockIdx.x < SCAT_B) {
        // ---- scatter branch ----
        int* cur = (int*)smem;
        int r = blockIdx.x % NR2, c = blockIdx.x / NR2;
        int lo = r * RSZ;
        for (int t = tid; t < RSZ; t += 256)
            cur[t] = rowptr[lo + t] + CntG[(size_t)c * NN + lo + t];
        __syncthreads();
        const int* __restrict__ dstp = ei + EE;
        int base = c * CSZ;
        for (int ii = 0; ii < CSZ; ii += 1024) {
            int off = ii + tid * 4;
            if (off < CSZ) {
                int4 s4 = *(const int4*)&ei[base + off];
                int4 d4 = *(const int4*)&dstp[base + off];
                int dl;
                dl = d4.x - lo; if (dl >= 0 && dl < RSZ && s4.x != d4.x) { int p = atomicAdd(&cur[dl], 1); col[p] = s4.x; }
                dl = d4.y - lo; if (dl >= 0 && dl < RSZ && s4.y != d4.y) { int p = atomicAdd(&cur[dl], 1); col[p] = s4.y; }
                dl = d4.z - lo; if (dl >= 0 && dl < RSZ && s4.z != d4.z) { int p = atomicAdd(&cur[dl], 1); col[p] = s4.z; }
                dl = d4.w - lo; if (dl >= 0 && dl < RSZ && s4.w != d4.w) { int p = atomicAdd(&cur[dl], 1); col[p] = s4.w; }
            }
        }
        return;
    }

    // ---- gemm1 branch: K=128, M=64, H=8, NPB=64 ----
    constexpr int K = 128, M = 64, Hh = 8, NPB = 64;
    constexpr int C   = M / Hh;              // 8
    constexpr int MG  = M / 4;               // 16
    constexpr int K4  = K / 4;               // 32
    constexpr int KC4 = 16;
    constexpr int NCH = K4 / KC4;            // 2

    float4* Wq = (float4*)smem;              // K * MG = 2048 float4 (32 KB)
    float4* Xq = Wq + K * MG;                // NPB * KC4 = 1024 float4 (16 KB)

    const float4* W4 = (const float4*)W;
    for (int i = tid; i < K * MG; i += 256) Wq[i] = W4[i];

    int node0 = (blockIdx.x - SCAT_B) * NPB;
    const float4* x4 = (const float4*)xin;

    int mg = tid % MG, ng = tid / MG;
    int nb = ng * 4;
    float acc[4][4];
    #pragma unroll
    for (int i = 0; i < 4; ++i)
        #pragma unroll
        for (int j = 0; j < 4; ++j) acc[i][j] = 0.f;

    for (int ch = 0; ch < NCH; ++ch) {
        __syncthreads();
        for (int i = tid; i < NPB * KC4; i += 256) {
            int n = i / KC4, k4l = i % KC4;
            int node = node0 + n;
            float4 v = make_float4(0.f, 0.f, 0.f, 0.f);
            if (node < NN) v = x4[(size_t)node * K4 + ch * KC4 + k4l];
            Xq[i] = v;
        }
        __syncthreads();
        #pragma unroll 4
        for (int k4 = 0; k4 < KC4; ++k4) {
            float4 xv[4], wv[4];
            #pragma unroll
            for (int i = 0; i < 4; ++i) xv[i] = Xq[(nb + i) * KC4 + k4];
            int kbase = (ch * KC4 + k4) * 4;
            #pragma unroll
            for (int kk = 0; kk < 4; ++kk) wv[kk] = Wq[(kbase + kk) * MG + mg];
            #pragma unroll
            for (int i = 0; i < 4; ++i) {
                const float* xf = (const float*)&xv[i];
                #pragma unroll
                for (int kk = 0; kk < 4; ++kk) {
                    const float* wf = (const float*)&wv[kk];
                    float xs = xf[kk];
                    acc[i][0] = fmaf(xs, wf[0], acc[i][0]);
                    acc[i][1] = fmaf(xs, wf[1], acc[i][1]);
                    acc[i][2] = fmaf(xs, wf[2], acc[i][2]);
                    acc[i][3] = fmaf(xs, wf[3], acc[i][3]);
                }
            }
        }
    }

    constexpr int TPH = C / 4;               // 2
    int head = mg / TPH;
    int c0   = (mg % TPH) * 4;
    float ad[4], as_[4];
    #pragma unroll
    for (int j = 0; j < 4; ++j) {
        ad[j]  = att[head * 2 * C + c0 + j];
        as_[j] = att[head * 2 * C + C + c0 + j];
    }
    #pragma unroll
    for (int i = 0; i < 4; ++i) {
        int node = node0 + nb + i;
        if (node < NN) {
            unsigned short us[4];
            #pragma unroll
            for (int j = 0; j < 4; ++j) {
                __hip_bfloat16 b = __float2bfloat16(acc[i][j]);
                us[j] = *(unsigned short*)&b;
            }
            uint2 pk;
            pk.x = (unsigned)us[0] | ((unsigned)us[1] << 16);
            pk.y = (unsigned)us[2] | ((unsigned)us[3] << 16);
            Hbf[(size_t)node * MG + mg] = pk;
        }
        float pd = acc[i][0]*ad[0]  + acc[i][1]*ad[1]  + acc[i][2]*ad[2]  + acc[i][3]*ad[3];
        float ps = acc[i][0]*as_[0] + acc[i][1]*as_[1] + acc[i][2]*as_[2] + acc[i][3]*as_[3];
        #pragma unroll
        for (int off = 1; off < TPH; off <<= 1) {
            pd += __shfl_xor(pd, off, 64);
            ps += __shfl_xor(ps, off, 64);
        }
        if ((mg % TPH) == 0 && node < NN) {
            sdst[node * Hh + head]  = pd;
            ssrcA[node * Hh + head] = ps;
        }
    }
}

// ---------------- Aggregation phase (grid-stride, round-2 proven body) --------

template<int CT, int H, int U, bool ELU_OUT>
__device__ void agg_phase(const int* __restrict__ rowptr, const int* __restrict__ col,
                          const float* __restrict__ sdst, const float* __restrict__ ssrcA,
                          const uint2* __restrict__ Hbf,
                          const float* __restrict__ bias, float* __restrict__ output) {
    constexpr int C    = CT / H;         // channels per head
    constexpr int CP   = CT / 4;         // lanes covering one row (uint2 = 4 ch)
    constexpr int G    = 64 / CP;        // edge slots per gather instruction
    constexpr int NL   = U / G;          // row gathers in flight per lane
    constexpr int EPEL = (U * H >= 64) ? (U * H) / 64 : 1;   // edges per exp lane
    static_assert(EPEL == 1 || EPEL == 2, "mapping");
    constexpr int NU   = (NN + 3) / 4;   // 4-node groups

    int lane = threadIdx.x & 63;
    int wid  = threadIdx.x >> 6;
    int cp = lane % CP;                  // channel quad {4cp..4cp+3}
    int pp = lane / CP;                  // gather slot parity (0..G-1)
    int hh = (4 * cp) / C;               // head of these channels (uniform in quad)
    int eh = lane % H;                   // exp-lane head
    int gb = lane / H;                   // exp-lane base edge slot
    bool elane = (lane < U * H);         // exp-lane mask (EPEL==1 case)

    for (int u = blockIdx.x; u < NU; u += gridDim.x) {
        int node = u * 4 + wid;
        if (node >= NN) continue;        // no barriers inside: safe divergence

        float sd = elane ? sdst[node * H + eh] : 0.f;
        int start = rowptr[node], end = rowptr[node + 1];

        // ---- virtual self-loop: score + own-row contribution (coalesced) ----
        float dsum = 0.f;
        float e_self = 0.f;
        if (lane < H) {                  // lane == eh, gb == 0
            float ss = ssrcA[node * H + lane];
            float a = sd + ss; a = (a >= 0.f) ? a : 0.2f * a;
            e_self = __expf(a);
            dsum = e_self;
        }
        uint2 hs = Hbf[(size_t)node * CP + cp];
        float exs = __shfl(e_self, hh, 64);
        float4 acc = make_float4(0.f, 0.f, 0.f, 0.f);
        if (pp == 0) {                   // count self row exactly once
            acc.x = exs * __uint_as_float(hs.x << 16);
            acc.y = exs * __uint_as_float(hs.x & 0xffff0000u);
            acc.z = exs * __uint_as_float(hs.y << 16);
            acc.w = exs * __uint_as_float(hs.y & 0xffff0000u);
        }

        // first col chunk
        int cv = node;
        if (start < end) {
            int idx = start + lane;
            if (lane < U && idx < end) cv = col[idx];
        }

        for (int j = start; j < end; j += U) {
            float s1 = 0.f, s2 = 0.f;
            int b1 = 0, b2 = 0;
            if (EPEL == 2) {
                b1 = __shfl(cv, gb, 64);
                b2 = __shfl(cv, gb + U / 2, 64);
                s1 = ssrcA[b1 * H + eh];
                s2 = ssrcA[b2 * H + eh];
            } else {
                b1 = __shfl(cv, gb, 64);
                if (elane) s1 = ssrcA[b1 * H + eh];
            }

            // issue ALL row gathers back-to-back (depend only on cv)
            uint2 hv[NL];
            #pragma unroll
            for (int t = 0; t < NL; ++t) {
                int se = __shfl(cv, t * G + pp, 64);
                hv[t] = Hbf[(size_t)se * CP + cp];
            }

            // prefetch next col chunk while gathers are in flight
            int jn = j + U;
            int cvN = node;
            if (jn < end) {
                int idx = jn + lane;
                if (lane < U && idx < end) cvN = col[idx];
            }

            // exps (consume ssrcA; Hbf gathers still in flight)
            float e1 = 0.f, e2 = 0.f;
            if (EPEL == 2) {
                float a1 = sd + s1; a1 = (a1 >= 0.f) ? a1 : 0.2f * a1;
                float a2 = sd + s2; a2 = (a2 >= 0.f) ? a2 : 0.2f * a2;
                if (j + gb < end)         e1 = __expf(a1);
                if (j + gb + U / 2 < end) e2 = __expf(a2);
                dsum += e1 + e2;
            } else {
                float a1 = sd + s1; a1 = (a1 >= 0.f) ? a1 : 0.2f * a1;
                if (elane && j + gb < end) { e1 = __expf(a1); dsum += e1; }
            }

            // consume gathers (dead slots have zero weight)
            #pragma unroll
            for (int t = 0; t < NL; ++t) {
                int eidx = t * G + pp;
                float ex;
                if (EPEL == 2)
                    ex = __shfl((t * G + G - 1 < U / 2) ? e1 : e2, (eidx & (U / 2 - 1)) * H + hh, 64);
                else
                    ex = __shfl(e1, eidx * H + hh, 64);
                float f0 = __uint_as_float(hv[t].x << 16);
                float f1 = __uint_as_float(hv[t].x & 0xffff0000u);
                float f2 = __uint_as_float(hv[t].y << 16);
                float f3 = __uint_as_float(hv[t].y & 0xffff0000u);
                acc.x = fmaf(ex, f0, acc.x);
                acc.y = fmaf(ex, f1, acc.y);
                acc.z = fmaf(ex, f2, acc.z);
                acc.w = fmaf(ex, f3, acc.w);
            }
            cv = cvN;
        }

        // reduce dsum over edge-slot lanes (masked lanes contribute 0)
        #pragma unroll
        for (int off = H; off < 64; off <<= 1) dsum += __shfl_xor(dsum, off, 64);
        float den = __shfl(dsum, hh, 64);
        #pragma unroll
        for (int off = CP; off < 64; off <<= 1) {
            acc.x += __shfl_xor(acc.x, off, 64);
            acc.y += __shfl_xor(acc.y, off, 64);
            acc.z += __shfl_xor(acc.z, off, 64);
            acc.w += __shfl_xor(acc.w, off, 64);
        }
        if (lane < CP) {
            float inv = 1.f / den;
            float4 bv = ((const float4*)bias)[cp];
            float4 v;
            v.x = acc.x * inv + bv.x;
            v.y = acc.y * inv + bv.y;
            v.z = acc.z * inv + bv.z;
            v.w = acc.w * inv + bv.w;
            if (ELU_OUT) {
                v.x = (v.x > 0.f) ? v.x : expm1f(v.x);   // ELU(alpha=1)
                v.y = (v.y > 0.f) ? v.y : expm1f(v.y);
                v.z = (v.z > 0.f) ? v.z : expm1f(v.z);
                v.w = (v.w > 0.f) ? v.w : expm1f(v.w);
            }
            ((float4*)output)[(size_t)node * CP + cp] = v;
        }
    }
}

// ---------------- GEMM phase (grid-stride, proven gemm_tile body) -------------

template<int K, int M, int H, int NPB, int KC4>
__device__ void gemm_phase(const float* __restrict__ xin,
                           const float* __restrict__ W,
                           const float* __restrict__ att,
                           uint2* __restrict__ Hbf,
                           float* __restrict__ ssrcA,
                           float* __restrict__ sdst,
                           float4* __restrict__ Wq, float4* __restrict__ Xq) {
    constexpr int C   = M / H;
    constexpr int MG  = M / 4;
    constexpr int NG  = NPB / 4;
    static_assert(MG * NG == 256, "tile mismatch");
    constexpr int K4  = K / 4;
    constexpr int NCH = K4 / KC4;
    constexpr int NT  = (NN + NPB - 1) / NPB;

    int tid = threadIdx.x;
    const float4* W4 = (const float4*)W;
    for (int i = tid; i < K * MG; i += 256) Wq[i] = W4[i];

    const float4* x4 = (const float4*)xin;
    int mg = tid % MG, ng = tid / MG;
    int nb = ng * 4;

    constexpr int TPH = C / 4;
    int head = mg / TPH;
    int c0   = (mg % TPH) * 4;
    float ad[4], as_[4];
    #pragma unroll
    for (int j = 0; j < 4; ++j) {
        ad[j]  = att[head * 2 * C + c0 + j];
        as_[j] = att[head * 2 * C + C + c0 + j];
    }

    for (int u = blockIdx.x; u < NT; u += gridDim.x) {
        int node0 = u * NPB;
        float acc[4][4];
        #pragma unroll
        for (int i = 0; i < 4; ++i)
            #pragma unroll
            for (int j = 0; j < 4; ++j) acc[i][j] = 0.f;

        for (int ch = 0; ch < NCH; ++ch) {
            __syncthreads();
            for (int i = tid; i < NPB * KC4; i += 256) {
                int n = i / KC4, k4l = i % KC4;
                int node = node0 + n;
                float4 v = make_float4(0.f, 0.f, 0.f, 0.f);
                if (node < NN) v = x4[(size_t)node * K4 + ch * KC4 + k4l];
                Xq[i] = v;
            }
            __syncthreads();
            #pragma unroll 4
            for (int k4 = 0; k4 < KC4; ++k4) {
                float4 xv[4], wv[4];
                #pragma unroll
                for (int i = 0; i < 4; ++i) xv[i] = Xq[(nb + i) * KC4 + k4];
                int kbase = (ch * KC4 + k4) * 4;
                #pragma unroll
                for (int kk = 0; kk < 4; ++kk) wv[kk] = Wq[(kbase + kk) * MG + mg];
                #pragma unroll
                for (int i = 0; i < 4; ++i) {
                    const float* xf = (const float*)&xv[i];
                    #pragma unroll
                    for (int kk = 0; kk < 4; ++kk) {
                        const float* wf = (const float*)&wv[kk];
                        float xs = xf[kk];
                        acc[i][0] = fmaf(xs, wf[0], acc[i][0]);
                        acc[i][1] = fmaf(xs, wf[1], acc[i][1]);
                        acc[i][2] = fmaf(xs, wf[2], acc[i][2]);
                        acc[i][3] = fmaf(xs, wf[3], acc[i][3]);
                    }
                }
            }
        }

        #pragma unroll
        for (int i = 0; i < 4; ++i) {
            int node = node0 + nb + i;
            if (node < NN) {
                unsigned short us[4];
                #pragma unroll
                for (int j = 0; j < 4; ++j) {
                    __hip_bfloat16 b = __float2bfloat16(acc[i][j]);
                    us[j] = *(unsigned short*)&b;
                }
                uint2 pk;
                pk.x = (unsigned)us[0] | ((unsigned)us[1] << 16);
                pk.y = (unsigned)us[2] | ((unsigned)us[3] << 16);
                Hbf[(size_t)node * MG + mg] = pk;
            }
            float pd = acc[i][0]*ad[0]  + acc[i][1]*ad[1]  + acc[i][2]*ad[2]  + acc[i][3]*ad[3];
            float ps = acc[i][0]*as_[0] + acc[i][1]*as_[1] + acc[i][2]*as_[2] + acc[i][3]*as_[3];
            #pragma unroll
            for (int off = 1; off < TPH; off <<= 1) {
                pd += __shfl_xor(pd, off, 64);
                ps += __shfl_xor(ps, off, 64);
            }
            if ((mg % TPH) == 0 && node < NN) {
                sdst[node * H + head]  = pd;
                ssrcA[node * H + head] = ps;
            }
        }
    }
}

// ---------------- Cooperative mega-kernel: the 5-phase layer chain -----------
// Phases separated by device-scope fence + grid.sync (the sanctioned cross-
// workgroup ordering mechanism). All phase bodies are the proven per-dispatch
// kernels, wrapped in grid-stride loops. 24 KB LDS union for the gemm phases.

__global__ __launch_bounds__(256, 5) void layers_k(
    const int* rowptr, const int* col,
    const float* sdst1, const float* ssrcA1, const uint2* Hbf1, const float* b1,
    float* Fb,
    const float* W2, const float* att2, uint2* Hbf2, float* ssrcA2, float* sdst2,
    const float* b2,
    const float* W3, const float* att3, uint2* Hbf3, float* ssrcA3, float* sdst3,
    const float* b3,
    float* out)
{
    __shared__ float4 smemU[1536];    // 24 KB: Wq+Xq union for gemm phases
    cg::grid_group grid = cg::this_grid();

    agg_phase<64, 8, 16, true>(rowptr, col, sdst1, ssrcA1, Hbf1, b1, Fb);
    __threadfence(); grid.sync(); __threadfence();

    gemm_phase<64, 64, 8, 64, 8>(Fb, W2, att2, Hbf2, ssrcA2, sdst2,
                                 smemU, smemU + 1024);
    __threadfence(); grid.sync(); __threadfence();

    agg_phase<64, 8, 16, true>(rowptr, col, sdst2, ssrcA2, Hbf2, b2, Fb);
    __threadfence(); grid.sync(); __threadfence();

    gemm_phase<64, 32, 1, 128, 8>(Fb, W3, att3, Hbf3, ssrcA3, sdst3,
                                  smemU, smemU + 512);
    __threadfence(); grid.sync(); __threadfence();

    agg_phase<32, 1, 32, false>(rowptr, col, sdst3, ssrcA3, Hbf3, b3, out);
}

// ---------------- Classic-path wrappers (fallback if no cooperative) ---------

template<int CT, int H, int U, bool ELU_OUT>
__global__ __launch_bounds__(256) void agg_w(const int* __restrict__ rowptr, const int* __restrict__ col,
                      const float* __restrict__ sdst, const float* __restrict__ ssrcA,
                      const uint2* __restrict__ Hbf,
                      const float* __restrict__ bias, float* __restrict__ output) {
    agg_phase<CT, H, U, ELU_OUT>(rowptr, col, sdst, ssrcA, Hbf, bias, output);
}

template<int K, int M, int H, int NPB, int KC4>
__global__ __launch_bounds__(256) void gemm_w(const float* __restrict__ xin,
                          const float* __restrict__ W, const float* __restrict__ att,
                          uint2* __restrict__ Hbf, float* __restrict__ ssrcA,
                          float* __restrict__ sdst) {
    __shared__ float4 smemU[1536];
    gemm_phase<K, M, H, NPB, KC4>(xin, W, att, Hbf, ssrcA, sdst,
                                  smemU, smemU + K * (M / 4));
}

// ---------------- launch ----------------

extern "C" void kernel_launch(void* const* d_in, const int* in_sizes, int n_in,
                              void* d_out, int out_size, void* d_ws, size_t ws_size,
                              hipStream_t stream) {
    const float* x    = (const float*)d_in[0];
    const int*   ei   = (const int*)d_in[1];
    const float* W1   = (const float*)d_in[2];
    const float* att1 = (const float*)d_in[3];
    const float* b1   = (const float*)d_in[4];
    const float* W2   = (const float*)d_in[5];
    const float* att2 = (const float*)d_in[6];
    const float* b2   = (const float*)d_in[7];
    const float* W3   = (const float*)d_in[8];
    const float* att3 = (const float*)d_in[9];
    const float* b3   = (const float*)d_in[10];
    float* out = (float*)d_out;

    char* p = (char*)d_ws;
    auto alloc = [&](size_t bytes) -> void* {
        void* r = (void*)p;
        p += (bytes + 255) & ~(size_t)255;
        return r;
    };
    int*   rowptr   = (int*)alloc((NN + 1) * sizeof(int));
    int*   deg      = (int*)alloc(NN * sizeof(int));
    int*   CntG     = (int*)alloc((size_t)CH * NN * sizeof(int));
    int*   partials = (int*)alloc(NB_SCAN * sizeof(int));
    int*   col      = (int*)alloc(EE * sizeof(int));
    float* sdst1    = (float*)alloc((size_t)NN * 8 * sizeof(float));
    float* ssrcA1   = (float*)alloc((size_t)NN * 8 * sizeof(float));
    uint2* Hbf1     = (uint2*)alloc((size_t)NN * 16 * sizeof(uint2));
    float* Fb       = (float*)alloc((size_t)NN * 64 * sizeof(float));
    float* sdst2    = (float*)alloc((size_t)NN * 8 * sizeof(float));
    float* ssrcA2   = (float*)alloc((size_t)NN * 8 * sizeof(float));
    uint2* Hbf2     = (uint2*)CntG;   // alias: CntG dead after sg1_k (12.8 MB each)
    uint2* Hbf3     = (uint2*)alloc((size_t)NN * 8 * sizeof(uint2));
    float* sdst3    = (float*)alloc((size_t)NN * sizeof(float));
    float* ssrcA3   = (float*)alloc((size_t)NN * sizeof(float));

    // --- CSR build front (3 dispatches) ---
    histL_k<<<CH * NR2, 256, 0, stream>>>(ei, CntG);
    combine_sum_k<<<NB_SCAN, 256, 0, stream>>>(CntG, deg, partials);
    scan_final<<<NB_SCAN, 256, 0, stream>>>(deg, partials, rowptr);

    // --- scatter || gemm1 (fused, union'd dynamic LDS) ---
    constexpr int SMEM = RSZ * (int)sizeof(int);   // 50000 B >= gemm's 48 KB
    sg1_k<<<SCAT_B + (NN + 63) / 64, 256, SMEM, stream>>>(ei, CntG, rowptr, col,
                                                          x, W1, att1, Hbf1, ssrcA1, sdst1);

    // --- cooperative capability check (host-only queries; cached) ---
    static int s_checked = 0, s_coop = 0, s_nblk = 0;
    if (!s_checked) {
        int dev = 0;
        hipGetDevice(&dev);
        int coop = 0;
        hipDeviceGetAttribute(&coop, hipDeviceAttributeCooperativeLaunch, dev);
        int mbpc = 0;
        hipOccupancyMaxActiveBlocksPerMultiprocessor(&mbpc, layers_k, 256, 0);
        hipDeviceProp_t prop;
        hipGetDeviceProperties(&prop, dev);
        int cap = mbpc * prop.multiProcessorCount;
        s_nblk = (cap > 1280) ? 1280 : cap;
        s_coop = (coop != 0 && s_nblk >= 256);
        s_checked = 1;
    }

    if (s_coop) {
        void* args[] = {
            (void*)&rowptr, (void*)&col,
            (void*)&sdst1, (void*)&ssrcA1, (void*)&Hbf1, (void*)&b1,
            (void*)&Fb,
            (void*)&W2, (void*)&att2, (void*)&Hbf2, (void*)&ssrcA2, (void*)&sdst2,
            (void*)&b2,
            (void*)&W3, (void*)&att3, (void*)&Hbf3, (void*)&ssrcA3, (void*)&sdst3,
            (void*)&b3,
            (void*)&out
        };
        hipLaunchCooperativeKernel(layers_k, dim3(s_nblk), dim3(256), args, 0, stream);
    } else {
        // classic 5-dispatch fallback (identical math)
        agg_w<64, 8, 16, true><<<(NN + 3) / 4, 256, 0, stream>>>(rowptr, col, sdst1, ssrcA1, Hbf1, b1, Fb);
        gemm_w<64, 64, 8, 64, 8><<<(NN + 63) / 64, 256, 0, stream>>>(Fb, W2, att2, Hbf2, ssrcA2, sdst2);
        agg_w<64, 8, 16, true><<<(NN + 3) / 4, 256, 0, stream>>>(rowptr, col, sdst2, ssrcA2, Hbf2, b2, Fb);
        gemm_w<64, 32, 1, 128, 8><<<(NN + 127) / 128, 256, 0, stream>>>(Fb, W3, att3, Hbf3, ssrcA3, sdst3);
        agg_w<32, 1, 32, false><<<(NN + 3) / 4, 256, 0, stream>>>(rowptr, col, sdst3, ssrcA3, Hbf3, b3, out);
    }
}

// Round 11
// 386.577 us; speedup vs baseline: 3.0375x; 3.0375x over previous
//
#include <hip/hip_runtime.h>
#include <hip/hip_bf16.h>

#define NN 100000
#define EE 1600000

constexpr int SCAN_BLK = 1024;                       // nodes per scan/combine block
constexpr int NB_SCAN  = (NN + SCAN_BLK - 1) / SCAN_BLK;  // 98

// LDS counting-sort CSR build: 8 dst-ranges x 32 edge-chunks
constexpr int NR2 = 8;              // dst ranges (12500 nodes -> 50 KB LDS histogram)
constexpr int RSZ = NN / NR2;       // 12500
constexpr int CH  = 32;             // edge chunks
constexpr int CSZ = EE / CH;        // 50000 edges per chunk (multiple of 4)
constexpr int SCAT_B = CH * NR2;    // 256 scatter blocks in the fused kernel

// ---------------- CSR build (no global atomics) ----------------
// histL_k block 0 also zeroes the lookback flag array for combine_scan_k
// (dispatch boundary guarantees visibility before combine_scan_k starts).

__global__ __launch_bounds__(256) void histL_k(const int* __restrict__ ei,
                                               int* __restrict__ CntG,
                                               int* __restrict__ flags) {
    __shared__ int cnt[RSZ];
    int r = blockIdx.x % NR2, c = blockIdx.x / NR2;
    int lo = r * RSZ;
    if (blockIdx.x == 0 && threadIdx.x < 128) flags[threadIdx.x] = 0;
    for (int t = threadIdx.x; t < RSZ; t += 256) cnt[t] = 0;
    __syncthreads();
    const int* __restrict__ dstp = ei + EE;
    int base = c * CSZ;
    int tid = threadIdx.x;
    for (int ii = 0; ii < CSZ; ii += 1024) {
        int off = ii + tid * 4;
        if (off < CSZ) {
            int4 s4 = *(const int4*)&ei[base + off];
            int4 d4 = *(const int4*)&dstp[base + off];
            int dl;
            dl = d4.x - lo; if (dl >= 0 && dl < RSZ && s4.x != d4.x) atomicAdd(&cnt[dl], 1);
            dl = d4.y - lo; if (dl >= 0 && dl < RSZ && s4.y != d4.y) atomicAdd(&cnt[dl], 1);
            dl = d4.z - lo; if (dl >= 0 && dl < RSZ && s4.z != d4.z) atomicAdd(&cnt[dl], 1);
            dl = d4.w - lo; if (dl >= 0 && dl < RSZ && s4.w != d4.w) atomicAdd(&cnt[dl], 1);
        }
    }
    __syncthreads();
    for (int t = threadIdx.x; t < RSZ; t += 256)
        CntG[(size_t)c * NN + lo + t] = cnt[t];
}

// ---------------- Fused combine + scan (decoupled lookback) ------------------
// Each block: (A) chunk-prefix transform over CntG for its 1024 nodes,
// collecting per-node degree in LDS; (B) block total; (C) publish total+1 into
// its pre-zeroed flag word (single-word payload+flag); (D) threads t<b poll
// predecessor t's word — aggregates are INDEPENDENT (no serial chain, no
// dispatch-order assumption; every block publishes before it waits, so there
// is no circular dependency); (E) block-local scan + rowptr write.

__global__ __launch_bounds__(256) void combine_scan_k(int* __restrict__ CntG,
                                                      int* __restrict__ flags,
                                                      int* __restrict__ rowptr) {
    __shared__ int degsh[SCAN_BLK];
    __shared__ int sh[256];
    int t = threadIdx.x;
    int b = blockIdx.x;

    // (A) combine transform, coalesced (node = b*1024 + k*256 + t)
    int s_tot = 0;
    #pragma unroll
    for (int k = 0; k < 4; ++k) {
        int d = b * SCAN_BLK + k * 256 + t;
        int run = 0;
        if (d < NN) {
            #pragma unroll 8
            for (int c = 0; c < CH; ++c) {
                int v = CntG[(size_t)c * NN + d];
                CntG[(size_t)c * NN + d] = run;
                run += v;
            }
        }
        degsh[k * 256 + t] = run;
        s_tot += run;
    }

    // (B) block total
    sh[t] = s_tot; __syncthreads();
    for (int off = 128; off > 0; off >>= 1) {
        if (t < off) sh[t] += sh[t + off];
        __syncthreads();
    }
    int stot = sh[0];

    // (C) publish (payload+flag in one word: value = sum+1, 0 = not ready)
    if (t == 0) {
        __threadfence();
        atomicExch(&flags[b], stot + 1);
    }

    // (D) lookback: thread t polls predecessor t (independent aggregates)
    int psum = 0;
    if (t < b) {
        int v;
        do { v = atomicAdd(&flags[t], 0); } while (v == 0);
        psum = v - 1;
    }
    __syncthreads();
    sh[t] = psum; __syncthreads();
    for (int off = 128; off > 0; off >>= 1) {
        if (t < off) sh[t] += sh[t + off];
        __syncthreads();
    }
    int pref0 = sh[0];
    __syncthreads();

    // (E) block-local inclusive scan (thread t owns contiguous nodes t*4..t*4+3)
    int v[4]; int s = 0;
    #pragma unroll
    for (int k = 0; k < 4; ++k) { v[k] = degsh[t * 4 + k]; s += v[k]; }
    sh[t] = s; __syncthreads();
    for (int off = 1; off < 256; off <<= 1) {
        int tmp = (t >= off) ? sh[t - off] : 0;
        __syncthreads();
        sh[t] += tmp;
        __syncthreads();
    }
    int pref = pref0 + sh[t] - s;
    #pragma unroll
    for (int k = 0; k < 4; ++k) {
        int i = b * SCAN_BLK + t * 4 + k;
        if (i < NN) {
            rowptr[i] = pref; pref += v[k];
            if (i == NN - 1) rowptr[NN] = pref;
        }
    }
}

// ---------------- Fused scatter (CSR col build) || gemm1 ----------------
// Verified in rounds 7-9. Blocks 0..255 run the LDS scatter; blocks 256.. run
// the layer-1 GEMM (x @ W1 + attention scores). Union'd dynamic LDS (50 KB).

__global__ __launch_bounds__(256) void sg1_k(const int* __restrict__ ei,
                                             const int* __restrict__ CntG,
                                             const int* __restrict__ rowptr,
                                             int* __restrict__ col,
                                             const float* __restrict__ xin,
                                             const float* __restrict__ W,
                                             const float* __restrict__ att,
                                             uint2* __restrict__ Hbf,
                                             float* __restrict__ ssrcA,
                                             float* __restrict__ sdst) {
    extern __shared__ char smem[];
    int tid = threadIdx.x;

    if (blockIdx.x < SCAT_B) {
        // ---- scatter branch ----
        int* cur = (int*)smem;
        int r = blockIdx.x % NR2, c = blockIdx.x / NR2;
        int lo = r * RSZ;
        for (int t = tid; t < RSZ; t += 256)
            cur[t] = rowptr[lo + t] + CntG[(size_t)c * NN + lo + t];
        __syncthreads();
        const int* __restrict__ dstp = ei + EE;
        int base = c * CSZ;
        for (int ii = 0; ii < CSZ; ii += 1024) {
            int off = ii + tid * 4;
            if (off < CSZ) {
                int4 s4 = *(const int4*)&ei[base + off];
                int4 d4 = *(const int4*)&dstp[base + off];
                int dl;
                dl = d4.x - lo; if (dl >= 0 && dl < RSZ && s4.x != d4.x) { int p = atomicAdd(&cur[dl], 1); col[p] = s4.x; }
                dl = d4.y - lo; if (dl >= 0 && dl < RSZ && s4.y != d4.y) { int p = atomicAdd(&cur[dl], 1); col[p] = s4.y; }
                dl = d4.z - lo; if (dl >= 0 && dl < RSZ && s4.z != d4.z) { int p = atomicAdd(&cur[dl], 1); col[p] = s4.z; }
                dl = d4.w - lo; if (dl >= 0 && dl < RSZ && s4.w != d4.w) { int p = atomicAdd(&cur[dl], 1); col[p] = s4.w; }
            }
        }
        return;
    }

    // ---- gemm1 branch: K=128, M=64, H=8, NPB=64 ----
    constexpr int K = 128, M = 64, Hh = 8, NPB = 64;
    constexpr int C   = M / Hh;              // 8
    constexpr int MG  = M / 4;               // 16
    constexpr int K4  = K / 4;               // 32
    constexpr int KC4 = 16;
    constexpr int NCH = K4 / KC4;            // 2

    float4* Wq = (float4*)smem;              // K * MG = 2048 float4 (32 KB)
    float4* Xq = Wq + K * MG;                // NPB * KC4 = 1024 float4 (16 KB)

    const float4* W4 = (const float4*)W;
    for (int i = tid; i < K * MG; i += 256) Wq[i] = W4[i];

    int node0 = (blockIdx.x - SCAT_B) * NPB;
    const float4* x4 = (const float4*)xin;

    int mg = tid % MG, ng = tid / MG;
    int nb = ng * 4;
    float acc[4][4];
    #pragma unroll
    for (int i = 0; i < 4; ++i)
        #pragma unroll
        for (int j = 0; j < 4; ++j) acc[i][j] = 0.f;

    for (int ch = 0; ch < NCH; ++ch) {
        __syncthreads();
        for (int i = tid; i < NPB * KC4; i += 256) {
            int n = i / KC4, k4l = i % KC4;
            int node = node0 + n;
            float4 v = make_float4(0.f, 0.f, 0.f, 0.f);
            if (node < NN) v = x4[(size_t)node * K4 + ch * KC4 + k4l];
            Xq[i] = v;
        }
        __syncthreads();
        #pragma unroll 4
        for (int k4 = 0; k4 < KC4; ++k4) {
            float4 xv[4], wv[4];
            #pragma unroll
            for (int i = 0; i < 4; ++i) xv[i] = Xq[(nb + i) * KC4 + k4];
            int kbase = (ch * KC4 + k4) * 4;
            #pragma unroll
            for (int kk = 0; kk < 4; ++kk) wv[kk] = Wq[(kbase + kk) * MG + mg];
            #pragma unroll
            for (int i = 0; i < 4; ++i) {
                const float* xf = (const float*)&xv[i];
                #pragma unroll
                for (int kk = 0; kk < 4; ++kk) {
                    const float* wf = (const float*)&wv[kk];
                    float xs = xf[kk];
                    acc[i][0] = fmaf(xs, wf[0], acc[i][0]);
                    acc[i][1] = fmaf(xs, wf[1], acc[i][1]);
                    acc[i][2] = fmaf(xs, wf[2], acc[i][2]);
                    acc[i][3] = fmaf(xs, wf[3], acc[i][3]);
                }
            }
        }
    }

    constexpr int TPH = C / 4;               // 2
    int head = mg / TPH;
    int c0   = (mg % TPH) * 4;
    float ad[4], as_[4];
    #pragma unroll
    for (int j = 0; j < 4; ++j) {
        ad[j]  = att[head * 2 * C + c0 + j];
        as_[j] = att[head * 2 * C + C + c0 + j];
    }
    #pragma unroll
    for (int i = 0; i < 4; ++i) {
        int node = node0 + nb + i;
        if (node < NN) {
            unsigned short us[4];
            #pragma unroll
            for (int j = 0; j < 4; ++j) {
                __hip_bfloat16 b = __float2bfloat16(acc[i][j]);
                us[j] = *(unsigned short*)&b;
            }
            uint2 pk;
            pk.x = (unsigned)us[0] | ((unsigned)us[1] << 16);
            pk.y = (unsigned)us[2] | ((unsigned)us[3] << 16);
            Hbf[(size_t)node * MG + mg] = pk;
        }
        float pd = acc[i][0]*ad[0]  + acc[i][1]*ad[1]  + acc[i][2]*ad[2]  + acc[i][3]*ad[3];
        float ps = acc[i][0]*as_[0] + acc[i][1]*as_[1] + acc[i][2]*as_[2] + acc[i][3]*as_[3];
        #pragma unroll
        for (int off = 1; off < TPH; off <<= 1) {
            pd += __shfl_xor(pd, off, 64);
            ps += __shfl_xor(ps, off, 64);
        }
        if ((mg % TPH) == 0 && node < NN) {
            sdst[node * Hh + head]  = pd;
            ssrcA[node * Hh + head] = ps;
        }
    }
}

// ---------------- GEMM (h = x @ W) + per-node attention arrays (layers 2,3) --

template<int K, int M, int H, int NPB>
__global__ __launch_bounds__(256) void gemm_tile(const float* __restrict__ xin,
                          const float* __restrict__ W,
                          const float* __restrict__ att,
                          uint2* __restrict__ Hbf,
                          float* __restrict__ ssrcA,
                          float* __restrict__ sdst) {
    constexpr int C   = M / H;
    constexpr int MG  = M / 4;               // col-groups (4 cols per thread)
    constexpr int NG  = NPB / 4;
    static_assert(MG * NG == 256, "tile mismatch");
    constexpr int K4  = K / 4;
    constexpr int KC4 = (K4 > 16) ? 16 : K4;
    constexpr int NCH = K4 / KC4;

    __shared__ float4 Wq[K * MG];
    __shared__ float4 Xq[NPB * KC4];

    int tid = threadIdx.x;
    const float4* W4 = (const float4*)W;
    for (int i = tid; i < K * MG; i += 256) Wq[i] = W4[i];

    int node0 = blockIdx.x * NPB;
    const float4* x4 = (const float4*)xin;

    int mg = tid % MG, ng = tid / MG;
    int nb = ng * 4;
    float acc[4][4];
    #pragma unroll
    for (int i = 0; i < 4; ++i)
        #pragma unroll
        for (int j = 0; j < 4; ++j) acc[i][j] = 0.f;

    for (int ch = 0; ch < NCH; ++ch) {
        __syncthreads();
        for (int i = tid; i < NPB * KC4; i += 256) {
            int n = i / KC4, k4l = i % KC4;
            int node = node0 + n;
            float4 v = make_float4(0.f, 0.f, 0.f, 0.f);
            if (node < NN) v = x4[(size_t)node * K4 + ch * KC4 + k4l];
            Xq[i] = v;
        }
        __syncthreads();
        #pragma unroll 4
        for (int k4 = 0; k4 < KC4; ++k4) {
            float4 xv[4], wv[4];
            #pragma unroll
            for (int i = 0; i < 4; ++i) xv[i] = Xq[(nb + i) * KC4 + k4];
            int kbase = (ch * KC4 + k4) * 4;
            #pragma unroll
            for (int kk = 0; kk < 4; ++kk) wv[kk] = Wq[(kbase + kk) * MG + mg];
            #pragma unroll
            for (int i = 0; i < 4; ++i) {
                const float* xf = (const float*)&xv[i];
                #pragma unroll
                for (int kk = 0; kk < 4; ++kk) {
                    const float* wf = (const float*)&wv[kk];
                    float xs = xf[kk];
                    acc[i][0] = fmaf(xs, wf[0], acc[i][0]);
                    acc[i][1] = fmaf(xs, wf[1], acc[i][1]);
                    acc[i][2] = fmaf(xs, wf[2], acc[i][2]);
                    acc[i][3] = fmaf(xs, wf[3], acc[i][3]);
                }
            }
        }
    }

    constexpr int TPH = C / 4;               // threads covering one head's cols
    int head = mg / TPH;
    int c0   = (mg % TPH) * 4;
    float ad[4], as_[4];
    #pragma unroll
    for (int j = 0; j < 4; ++j) {
        ad[j]  = att[head * 2 * C + c0 + j];
        as_[j] = att[head * 2 * C + C + c0 + j];
    }
    #pragma unroll
    for (int i = 0; i < 4; ++i) {
        int node = node0 + nb + i;
        if (node < NN) {
            unsigned short us[4];
            #pragma unroll
            for (int j = 0; j < 4; ++j) {
                __hip_bfloat16 b = __float2bfloat16(acc[i][j]);
                us[j] = *(unsigned short*)&b;
            }
            uint2 pk;
            pk.x = (unsigned)us[0] | ((unsigned)us[1] << 16);
            pk.y = (unsigned)us[2] | ((unsigned)us[3] << 16);
            Hbf[(size_t)node * MG + mg] = pk;
        }
        float pd = acc[i][0]*ad[0]  + acc[i][1]*ad[1]  + acc[i][2]*ad[2]  + acc[i][3]*ad[3];
        float ps = acc[i][0]*as_[0] + acc[i][1]*as_[1] + acc[i][2]*as_[2] + acc[i][3]*as_[3];
        #pragma unroll
        for (int off = 1; off < TPH; off <<= 1) {
            pd += __shfl_xor(pd, off, 64);
            ps += __shfl_xor(ps, off, 64);
        }
        if ((mg % TPH) == 0 && node < NN) {
            sdst[node * H + head]  = pd;
            ssrcA[node * H + head] = ps;
        }
    }
}

// ---------------- Aggregation: one wave per node (round-2 config, 59.2 us) ----
// 100K waves, unconditional clamped gathers, predicated-exp masking.

template<int CT, int H, int U, bool ELU_OUT>
__global__ __launch_bounds__(256) void agg_k(const int* __restrict__ rowptr, const int* __restrict__ col,
                      const float* __restrict__ sdst, const float* __restrict__ ssrcA,
                      const uint2* __restrict__ Hbf,
                      const float* __restrict__ bias, float* __restrict__ output) {
    constexpr int C    = CT / H;         // channels per head
    constexpr int CP   = CT / 4;         // lanes covering one row (uint2 = 4 ch)
    constexpr int G    = 64 / CP;        // edge slots per gather instruction
    constexpr int NL   = U / G;          // row gathers in flight per lane
    constexpr int EPEL = (U * H >= 64) ? (U * H) / 64 : 1;   // edges per exp lane
    static_assert(EPEL == 1 || EPEL == 2, "mapping");

    int lane = threadIdx.x & 63;
    int node = blockIdx.x * (blockDim.x >> 6) + (threadIdx.x >> 6);
    if (node >= NN) return;

    int cp = lane % CP;                  // channel quad {4cp..4cp+3}
    int pp = lane / CP;                  // gather slot parity (0..G-1)
    int hh = (4 * cp) / C;               // head of these channels (uniform in quad)
    int eh = lane % H;                   // exp-lane head
    int gb = lane / H;                   // exp-lane base edge slot
    bool elane = (lane < U * H);         // exp-lane mask (EPEL==1 case)

    float sd = elane ? sdst[node * H + eh] : 0.f;

    int start = rowptr[node], end = rowptr[node + 1];

    // ---- virtual self-loop: score + own-row contribution (coalesced) ----
    float dsum = 0.f;
    float e_self = 0.f;
    if (lane < H) {                      // lane == eh, gb == 0
        float ss = ssrcA[node * H + lane];
        float a = sd + ss; a = (a >= 0.f) ? a : 0.2f * a;
        e_self = __expf(a);
        dsum = e_self;
    }
    uint2 hs = Hbf[(size_t)node * CP + cp];
    float exs = __shfl(e_self, hh, 64);
    float4 acc = make_float4(0.f, 0.f, 0.f, 0.f);
    if (pp == 0) {                       // count self row exactly once
        acc.x = exs * __uint_as_float(hs.x << 16);
        acc.y = exs * __uint_as_float(hs.x & 0xffff0000u);
        acc.z = exs * __uint_as_float(hs.y << 16);
        acc.w = exs * __uint_as_float(hs.y & 0xffff0000u);
    }

    // first col chunk
    int cv = node;
    if (start < end) {
        int idx = start + lane;
        if (lane < U && idx < end) cv = col[idx];
    }

    for (int j = start; j < end; j += U) {
        // shuffles of current col chunk (feed both ssrcA and Hbf addressing)
        float s1 = 0.f, s2 = 0.f;
        int b1 = 0, b2 = 0;
        if (EPEL == 2) {
            b1 = __shfl(cv, gb, 64);
            b2 = __shfl(cv, gb + U / 2, 64);
            s1 = ssrcA[b1 * H + eh];     // issued; dead slots clamped to node (cached)
            s2 = ssrcA[b2 * H + eh];
        } else {
            b1 = __shfl(cv, gb, 64);
            if (elane) s1 = ssrcA[b1 * H + eh];
        }

        // issue ALL row gathers back-to-back (depend only on cv)
        uint2 hv[NL];
        #pragma unroll
        for (int t = 0; t < NL; ++t) {
            int se = __shfl(cv, t * G + pp, 64);
            hv[t] = Hbf[(size_t)se * CP + cp];
        }

        // prefetch next col chunk while gathers are in flight
        int jn = j + U;
        int cvN = node;
        if (jn < end) {                  // wave-uniform; after gather issue
            int idx = jn + lane;
            if (lane < U && idx < end) cvN = col[idx];
        }

        // exps (consume ssrcA; Hbf gathers still in flight)
        float e1 = 0.f, e2 = 0.f;
        if (EPEL == 2) {
            float a1 = sd + s1; a1 = (a1 >= 0.f) ? a1 : 0.2f * a1;
            float a2 = sd + s2; a2 = (a2 >= 0.f) ? a2 : 0.2f * a2;
            if (j + gb < end)         e1 = __expf(a1);
            if (j + gb + U / 2 < end) e2 = __expf(a2);
            dsum += e1 + e2;
        } else {
            float a1 = sd + s1; a1 = (a1 >= 0.f) ? a1 : 0.2f * a1;
            if (elane && j + gb < end) { e1 = __expf(a1); dsum += e1; }
        }

        // consume gathers (dead slots have zero weight)
        #pragma unroll
        for (int t = 0; t < NL; ++t) {
            int eidx = t * G + pp;
            float ex;
            if (EPEL == 2)
                ex = __shfl((t * G + G - 1 < U / 2) ? e1 : e2, (eidx & (U / 2 - 1)) * H + hh, 64);
            else
                ex = __shfl(e1, eidx * H + hh, 64);
            float f0 = __uint_as_float(hv[t].x << 16);
            float f1 = __uint_as_float(hv[t].x & 0xffff0000u);
            float f2 = __uint_as_float(hv[t].y << 16);
            float f3 = __uint_as_float(hv[t].y & 0xffff0000u);
            acc.x = fmaf(ex, f0, acc.x);
            acc.y = fmaf(ex, f1, acc.y);
            acc.z = fmaf(ex, f2, acc.z);
            acc.w = fmaf(ex, f3, acc.w);
        }
        cv = cvN;
    }

    // reduce dsum over edge-slot lanes (masked lanes contribute 0)
    #pragma unroll
    for (int off = H; off < 64; off <<= 1) dsum += __shfl_xor(dsum, off, 64);
    float den = __shfl(dsum, hh, 64);    // lane 'hh' holds head hh's full sum
    // reduce acc over gather-slot parities
    #pragma unroll
    for (int off = CP; off < 64; off <<= 1) {
        acc.x += __shfl_xor(acc.x, off, 64);
        acc.y += __shfl_xor(acc.y, off, 64);
        acc.z += __shfl_xor(acc.z, off, 64);
        acc.w += __shfl_xor(acc.w, off, 64);
    }
    if (lane < CP) {
        float inv = 1.f / den;
        float4 bv = ((const float4*)bias)[cp];
        float4 v;
        v.x = acc.x * inv + bv.x;
        v.y = acc.y * inv + bv.y;
        v.z = acc.z * inv + bv.z;
        v.w = acc.w * inv + bv.w;
        if (ELU_OUT) {
            v.x = (v.x > 0.f) ? v.x : expm1f(v.x);   // ELU(alpha=1)
            v.y = (v.y > 0.f) ? v.y : expm1f(v.y);
            v.z = (v.z > 0.f) ? v.z : expm1f(v.z);
            v.w = (v.w > 0.f) ? v.w : expm1f(v.w);
        }
        ((float4*)output)[(size_t)node * CP + cp] = v;
    }
}

// ---------------- launch ----------------

extern "C" void kernel_launch(void* const* d_in, const int* in_sizes, int n_in,
                              void* d_out, int out_size, void* d_ws, size_t ws_size,
                              hipStream_t stream) {
    const float* x    = (const float*)d_in[0];
    const int*   ei   = (const int*)d_in[1];
    const float* W1   = (const float*)d_in[2];
    const float* att1 = (const float*)d_in[3];
    const float* b1   = (const float*)d_in[4];
    const float* W2   = (const float*)d_in[5];
    const float* att2 = (const float*)d_in[6];
    const float* b2   = (const float*)d_in[7];
    const float* W3   = (const float*)d_in[8];
    const float* att3 = (const float*)d_in[9];
    const float* b3   = (const float*)d_in[10];
    float* out = (float*)d_out;

    char* p = (char*)d_ws;
    auto alloc = [&](size_t bytes) -> void* {
        void* r = (void*)p;
        p += (bytes + 255) & ~(size_t)255;
        return r;
    };
    int*   rowptr   = (int*)alloc((NN + 1) * sizeof(int));
    int*   flags    = (int*)alloc(128 * sizeof(int));
    int*   CntG     = (int*)alloc((size_t)CH * NN * sizeof(int));
    int*   col      = (int*)alloc(EE * sizeof(int));
    float* sdst     = (float*)alloc((size_t)NN * 8 * sizeof(float));
    float* ssrcA    = (float*)alloc((size_t)NN * 8 * sizeof(float));
    uint2* Hbf      = (uint2*)alloc((size_t)NN * 16 * sizeof(uint2));
    float* Fb       = (float*)alloc((size_t)NN * 64 * sizeof(float));

    // --- CSR build front (2 dispatches: hist, fused combine+scan) ---
    histL_k<<<CH * NR2, 256, 0, stream>>>(ei, CntG, flags);
    combine_scan_k<<<NB_SCAN, 256, 0, stream>>>(CntG, flags, rowptr);

    // --- scatter || gemm1 (fused, union'd dynamic LDS) ---
    constexpr int SMEM = RSZ * (int)sizeof(int);   // 50000 B >= gemm's 48 KB
    sg1_k<<<SCAT_B + (NN + 63) / 64, 256, SMEM, stream>>>(ei, CntG, rowptr, col,
                                                          x, W1, att1, Hbf, ssrcA, sdst);

    // --- Layer 1 agg -> Fb ---
    agg_k<64, 8, 16, true><<<(NN + 3) / 4, 256, 0, stream>>>(rowptr, col, sdst, ssrcA, Hbf, b1, Fb);

    // --- Layer 2: Fb[N,64] -> h[N,64]; H=8, C=8; ELU out -> Fb ---
    gemm_tile<64, 64, 8, 64><<<(NN + 63) / 64, 256, 0, stream>>>(Fb, W2, att2, Hbf, ssrcA, sdst);
    agg_k<64, 8, 16, true><<<(NN + 3) / 4, 256, 0, stream>>>(rowptr, col, sdst, ssrcA, Hbf, b2, Fb);

    // --- Layer 3: Fb[N,64] -> h[N,32]; H=1, C=32; no ELU, f32 out -> d_out ---
    gemm_tile<64, 32, 1, 128><<<(NN + 127) / 128, 256, 0, stream>>>(Fb, W3, att3, Hbf, ssrcA, sdst);
    agg_k<32, 1, 32, false><<<(NN + 3) / 4, 256, 0, stream>>>(rowptr, col, sdst, ssrcA, Hbf, b3, out);
}